// Round 1
// baseline (5293.823 us; speedup 1.0000x reference)
//
#include <hip/hip_runtime.h>
#include <hip/hip_bf16.h>

// ---------- helpers ----------
__device__ __forceinline__ float bf2f(unsigned short u) {
    union { unsigned int i; float f; } x; x.i = ((unsigned int)u) << 16; return x.f;
}
__device__ __forceinline__ unsigned short f2bf(float f) {
    union { float f; unsigned int i; } x; x.f = f;
    unsigned int r = x.i + 0x7fffu + ((x.i >> 16) & 1u);   // RTNE
    return (unsigned short)(r >> 16);
}
__device__ __forceinline__ float sigm(float x) { return 1.0f / (1.0f + __expf(-x)); }
__device__ __forceinline__ float ftanh(float x) {
    x = fminf(15.f, fmaxf(-15.f, x));
    float t = __expf(2.0f * x);
    return (t - 1.0f) / (t + 1.0f);
}

// ---------- input-projection GEMM: G[t*512+b][g] = A[b,t,:]·W[g,:] + bih[g]+bhh[g] ----------
// A row order: m = t*512 + b ; A element (b,t,k) at (b*128+t)*K
// grid: x = 1024/64 = 16 N-tiles, y = 65536/64 = 1024 M-tiles; 256 threads
template<int K, bool ABF16>
__global__ __launch_bounds__(256) void gemm_gates(
    const void* __restrict__ Ain, const float* __restrict__ W,
    const float* __restrict__ bih, const float* __restrict__ bhh,
    unsigned short* __restrict__ G)
{
    __shared__ float As[32][260];   // quad-major: As[q][r*4+ci] = A[m0+r][kk+q*4+ci]
    __shared__ float Bs[32][260];
    const int lid = threadIdx.x;
    const int tx = lid & 15, ty = lid >> 4;
    const int n0 = blockIdx.x * 64, m0 = blockIdx.y * 64;
    float acc[4][4] = {};

    for (int kk = 0; kk < K; kk += 128) {
        // stage A: 64 rows x 32 quads
        #pragma unroll
        for (int it = 0; it < 8; ++it) {
            int idx = lid + it * 256;
            int r = idx >> 5, q = idx & 31;
            int m = m0 + r;
            int t = m >> 9, b = m & 511;
            size_t src = ((size_t)b * 128 + t) * K + kk + q * 4;
            float4 v;
            if (ABF16) {
                ushort4 u = *(const ushort4*)((const unsigned short*)Ain + src);
                v.x = bf2f(u.x); v.y = bf2f(u.y); v.z = bf2f(u.z); v.w = bf2f(u.w);
            } else {
                v = *(const float4*)((const float*)Ain + src);
            }
            *(float4*)&As[q][r * 4] = v;
        }
        // stage B (weights)
        #pragma unroll
        for (int it = 0; it < 8; ++it) {
            int idx = lid + it * 256;
            int r = idx >> 5, q = idx & 31;
            int g = n0 + r;
            float4 v = *(const float4*)&W[(size_t)g * K + kk + q * 4];
            *(float4*)&Bs[q][r * 4] = v;
        }
        __syncthreads();
        #pragma unroll 4
        for (int q = 0; q < 32; ++q) {
            float4 a[4], b[4];
            #pragma unroll
            for (int i = 0; i < 4; ++i) a[i] = *(const float4*)&As[q][(ty * 4 + i) * 4];
            #pragma unroll
            for (int j = 0; j < 4; ++j) b[j] = *(const float4*)&Bs[q][(tx * 4 + j) * 4];
            #pragma unroll
            for (int i = 0; i < 4; ++i)
                #pragma unroll
                for (int j = 0; j < 4; ++j)
                    acc[i][j] += a[i].x * b[j].x + a[i].y * b[j].y
                               + a[i].z * b[j].z + a[i].w * b[j].w;
        }
        __syncthreads();
    }
    #pragma unroll
    for (int i = 0; i < 4; ++i) {
        int m = m0 + ty * 4 + i;
        int n = n0 + tx * 4;
        ushort4 o;
        o.x = f2bf(acc[i][0] + bih[n + 0] + bhh[n + 0]);
        o.y = f2bf(acc[i][1] + bih[n + 1] + bhh[n + 1]);
        o.z = f2bf(acc[i][2] + bih[n + 2] + bhh[n + 2]);
        o.w = f2bf(acc[i][3] + bih[n + 3] + bhh[n + 3]);
        *(ushort4*)&G[(size_t)m * 1024 + n] = o;
    }
}

// ---------- one LSTM timestep ----------
// grid: x = 32 j-chunks (8 cols each), y = 8 batch-chunks (64 rows each); 256 threads
__global__ __launch_bounds__(256) void lstm_step(
    const unsigned short* __restrict__ Gt,   // G + t*512*1024, [b][1024] bf16 (bias included)
    const float* __restrict__ Whh,           // [1024][256]
    const float* __restrict__ h_in, float* __restrict__ h_out,
    float* __restrict__ c,
    unsigned short* __restrict__ h0out)      // h0_all + t*256 (layer0) or nullptr
{
    __shared__ float hs[64][260];
    __shared__ float Ws[32][260];
    const int lid = threadIdx.x;
    const int jc = blockIdx.x;
    const int bc = blockIdx.y;

    // stage h chunk [64][256]
    #pragma unroll
    for (int it = 0; it < 16; ++it) {
        int idx = lid + it * 256;
        int bl = idx >> 6, q = idx & 63;
        float4 v = *(const float4*)&h_in[(size_t)(bc * 64 + bl) * 256 + q * 4];
        *(float4*)&hs[bl][q * 4] = v;
    }
    // stage Whh rows {type*256 + jc*8 + jj}, type 0..3, jj 0..7 -> Ws[type*8+jj][:]
    #pragma unroll
    for (int it = 0; it < 8; ++it) {
        int idx = lid + it * 256;
        int r = idx >> 6, q = idx & 63;
        int type = r >> 3, jj = r & 7;
        int grow = type * 256 + jc * 8 + jj;
        *(float4*)&Ws[r][q * 4] = *(const float4*)&Whh[(size_t)grow * 256 + q * 4];
    }
    __syncthreads();

    const int j  = lid & 7;
    const int bp = lid >> 3;      // 0..31
    const int b0 = bp * 2;
    float acc0[4] = {0.f, 0.f, 0.f, 0.f};
    float acc1[4] = {0.f, 0.f, 0.f, 0.f};
    #pragma unroll 4
    for (int q = 0; q < 64; ++q) {
        float4 h0v = *(const float4*)&hs[b0][q * 4];
        float4 h1v = *(const float4*)&hs[b0 + 1][q * 4];
        #pragma unroll
        for (int tpe = 0; tpe < 4; ++tpe) {
            float4 w = *(const float4*)&Ws[tpe * 8 + j][q * 4];
            acc0[tpe] += h0v.x * w.x + h0v.y * w.y + h0v.z * w.z + h0v.w * w.w;
            acc1[tpe] += h1v.x * w.x + h1v.y * w.y + h1v.z * w.z + h1v.w * w.w;
        }
    }

    const int jg = jc * 8 + j;
    #pragma unroll
    for (int s = 0; s < 2; ++s) {
        const float* acc = (s == 0) ? acc0 : acc1;
        int bg = bc * 64 + b0 + s;
        float pre[4];
        #pragma unroll
        for (int tpe = 0; tpe < 4; ++tpe)
            pre[tpe] = acc[tpe] + bf2f(Gt[(size_t)bg * 1024 + tpe * 256 + jg]);
        float ig = sigm(pre[0]);
        float ff = sigm(pre[1]);
        float gg = ftanh(pre[2]);
        float oo = sigm(pre[3]);
        size_t ci = (size_t)bg * 256 + jg;
        float cn = ff * c[ci] + ig * gg;
        c[ci] = cn;
        float hn = oo * ftanh(cn);
        h_out[ci] = hn;
        if (h0out) h0out[(size_t)bg * (128 * 256) + jg] = f2bf(hn);
    }
}

// ---------- FC GEMM: logits[m][n] = h[m,:]·fcW[n,:] + fcb[n] ----------
// grid: x = 786 N-tiles, y = 8 M-tiles
__global__ __launch_bounds__(256) void gemm_fc(
    const float* __restrict__ h, const float* __restrict__ fcW,
    const float* __restrict__ fcb, float* __restrict__ logits)
{
    __shared__ float As[32][260];
    __shared__ float Bs[32][260];
    const int lid = threadIdx.x;
    const int tx = lid & 15, ty = lid >> 4;
    const int n0 = blockIdx.x * 64, m0 = blockIdx.y * 64;
    float acc[4][4] = {};

    for (int kk = 0; kk < 256; kk += 128) {
        #pragma unroll
        for (int it = 0; it < 8; ++it) {
            int idx = lid + it * 256;
            int r = idx >> 5, q = idx & 31;
            int m = m0 + r;
            *(float4*)&As[q][r * 4] = *(const float4*)&h[(size_t)m * 256 + kk + q * 4];
        }
        #pragma unroll
        for (int it = 0; it < 8; ++it) {
            int idx = lid + it * 256;
            int r = idx >> 5, q = idx & 31;
            int g = n0 + r;
            float4 v = make_float4(0.f, 0.f, 0.f, 0.f);
            if (g < 50257) v = *(const float4*)&fcW[(size_t)g * 256 + kk + q * 4];
            *(float4*)&Bs[q][r * 4] = v;
        }
        __syncthreads();
        #pragma unroll 4
        for (int q = 0; q < 32; ++q) {
            float4 a[4], b[4];
            #pragma unroll
            for (int i = 0; i < 4; ++i) a[i] = *(const float4*)&As[q][(ty * 4 + i) * 4];
            #pragma unroll
            for (int j = 0; j < 4; ++j) b[j] = *(const float4*)&Bs[q][(tx * 4 + j) * 4];
            #pragma unroll
            for (int i = 0; i < 4; ++i)
                #pragma unroll
                for (int j = 0; j < 4; ++j)
                    acc[i][j] += a[i].x * b[j].x + a[i].y * b[j].y
                               + a[i].z * b[j].z + a[i].w * b[j].w;
        }
        __syncthreads();
    }
    #pragma unroll
    for (int i = 0; i < 4; ++i) {
        int m = m0 + ty * 4 + i;
        #pragma unroll
        for (int jj = 0; jj < 4; ++jj) {
            int n = n0 + tx * 4 + jj;
            if (n < 50257)
                logits[(size_t)m * 50257 + n] = acc[i][jj] + fcb[n];
        }
    }
}

// ---------- row softmax over 50257 ----------
__global__ __launch_bounds__(256) void softmax_rows(
    const float* __restrict__ logits, float* __restrict__ out)
{
    const int b = blockIdx.x;
    const int lid = threadIdx.x;
    const float* row = logits + (size_t)b * 50257;
    __shared__ float red[256];

    float m = -3.4e38f;
    for (int v = lid; v < 50257; v += 256) m = fmaxf(m, row[v]);
    red[lid] = m; __syncthreads();
    for (int s = 128; s > 0; s >>= 1) {
        if (lid < s) red[lid] = fmaxf(red[lid], red[lid + s]);
        __syncthreads();
    }
    m = red[0]; __syncthreads();

    float sum = 0.f;
    for (int v = lid; v < 50257; v += 256) sum += __expf(row[v] - m);
    red[lid] = sum; __syncthreads();
    for (int s = 128; s > 0; s >>= 1) {
        if (lid < s) red[lid] += red[lid + s];
        __syncthreads();
    }
    float inv = 1.0f / red[0];

    float* orow = out + (size_t)b * 50257;
    for (int v = lid; v < 50257; v += 256) orow[v] = __expf(row[v] - m) * inv;
}

// ---------- host ----------
extern "C" void kernel_launch(void* const* d_in, const int* in_sizes, int n_in,
                              void* d_out, int out_size, void* d_ws, size_t ws_size,
                              hipStream_t stream) {
    (void)in_sizes; (void)n_in; (void)out_size; (void)ws_size;
    const float* x    = (const float*)d_in[0];
    const float* Wih0 = (const float*)d_in[1];
    const float* Whh0 = (const float*)d_in[2];
    const float* bih0 = (const float*)d_in[3];
    const float* bhh0 = (const float*)d_in[4];
    const float* Wih1 = (const float*)d_in[5];
    const float* Whh1 = (const float*)d_in[6];
    const float* bih1 = (const float*)d_in[7];
    const float* bhh1 = (const float*)d_in[8];
    const float* fcW  = (const float*)d_in[9];
    const float* fcb  = (const float*)d_in[10];
    float* out = (float*)d_out;

    char* ws = (char*)d_ws;
    unsigned short* G     = (unsigned short*)ws;                    // 128*512*1024 bf16 = 134,217,728 B
    unsigned short* h0all = (unsigned short*)(ws + 134217728);      // 512*128*256 bf16 = 33,554,432 B
    float* hA = (float*)(ws + 167772160);                           // 512*256 f32
    float* hB = (float*)(ws + 168296448);
    float* cb = (float*)(ws + 168820736);
    float* logits = (float*)ws;                                     // reuse G region (103 MB < 134 MB)

    // ----- layer 0 -----
    hipMemsetAsync(hA, 0, 512 * 256 * 4, stream);
    hipMemsetAsync(cb, 0, 512 * 256 * 4, stream);
    gemm_gates<128, false><<<dim3(16, 1024), 256, 0, stream>>>(x, Wih0, bih0, bhh0, G);
    float* hi = hA; float* ho = hB;
    for (int t = 0; t < 128; ++t) {
        lstm_step<<<dim3(32, 8), 256, 0, stream>>>(
            G + (size_t)t * 512 * 1024, Whh0, hi, ho, cb, h0all + (size_t)t * 256);
        float* tmp = hi; hi = ho; ho = tmp;
    }
    // ----- layer 1 -----
    hipMemsetAsync(hi, 0, 512 * 256 * 4, stream);
    hipMemsetAsync(cb, 0, 512 * 256 * 4, stream);
    gemm_gates<256, true><<<dim3(16, 1024), 256, 0, stream>>>(h0all, Wih1, bih1, bhh1, G);
    for (int t = 0; t < 128; ++t) {
        lstm_step<<<dim3(32, 8), 256, 0, stream>>>(
            G + (size_t)t * 512 * 1024, Whh1, hi, ho, cb, nullptr);
        float* tmp = hi; hi = ho; ho = tmp;
    }
    // ----- FC + softmax -----
    gemm_fc<<<dim3(786, 8), 256, 0, stream>>>(hi, fcW, fcb, logits);
    softmax_rows<<<512, 256, 0, stream>>>(logits, out);
}

// Round 2
// 3578.555 us; speedup vs baseline: 1.4793x; 1.4793x over previous
//
#include <hip/hip_runtime.h>
#include <hip/hip_bf16.h>

// ---------- helpers ----------
__device__ __forceinline__ float bf2f(unsigned short u) {
    union { unsigned int i; float f; } x; x.i = ((unsigned int)u) << 16; return x.f;
}
__device__ __forceinline__ unsigned short f2bf(float f) {
    union { float f; unsigned int i; } x; x.f = f;
    unsigned int r = x.i + 0x7fffu + ((x.i >> 16) & 1u);   // RTNE
    return (unsigned short)(r >> 16);
}
__device__ __forceinline__ float sigm(float x) { return 1.0f / (1.0f + __expf(-x)); }
__device__ __forceinline__ float ftanh(float x) {
    x = fminf(15.f, fmaxf(-15.f, x));
    float t = __expf(2.0f * x);
    return (t - 1.0f) / (t + 1.0f);
}

typedef __attribute__((ext_vector_type(8))) short bf16x8;
typedef __attribute__((ext_vector_type(4))) float f32x4;

// ---------- input-projection GEMM: G[t*512+b][g] = A[b,t,:]·W[g,:] + bih[g]+bhh[g] ----------
template<int K, bool ABF16>
__global__ __launch_bounds__(256) void gemm_gates(
    const void* __restrict__ Ain, const float* __restrict__ W,
    const float* __restrict__ bih, const float* __restrict__ bhh,
    unsigned short* __restrict__ G)
{
    __shared__ float As[32][260];
    __shared__ float Bs[32][260];
    const int lid = threadIdx.x;
    const int tx = lid & 15, ty = lid >> 4;
    const int n0 = blockIdx.x * 64, m0 = blockIdx.y * 64;
    float acc[4][4] = {};

    for (int kk = 0; kk < K; kk += 128) {
        #pragma unroll
        for (int it = 0; it < 8; ++it) {
            int idx = lid + it * 256;
            int r = idx >> 5, q = idx & 31;
            int m = m0 + r;
            int t = m >> 9, b = m & 511;
            size_t src = ((size_t)b * 128 + t) * K + kk + q * 4;
            float4 v;
            if (ABF16) {
                ushort4 u = *(const ushort4*)((const unsigned short*)Ain + src);
                v.x = bf2f(u.x); v.y = bf2f(u.y); v.z = bf2f(u.z); v.w = bf2f(u.w);
            } else {
                v = *(const float4*)((const float*)Ain + src);
            }
            *(float4*)&As[q][r * 4] = v;
        }
        #pragma unroll
        for (int it = 0; it < 8; ++it) {
            int idx = lid + it * 256;
            int r = idx >> 5, q = idx & 31;
            int g = n0 + r;
            float4 v = *(const float4*)&W[(size_t)g * K + kk + q * 4];
            *(float4*)&Bs[q][r * 4] = v;
        }
        __syncthreads();
        #pragma unroll 4
        for (int q = 0; q < 32; ++q) {
            float4 a[4], b[4];
            #pragma unroll
            for (int i = 0; i < 4; ++i) a[i] = *(const float4*)&As[q][(ty * 4 + i) * 4];
            #pragma unroll
            for (int j = 0; j < 4; ++j) b[j] = *(const float4*)&Bs[q][(tx * 4 + j) * 4];
            #pragma unroll
            for (int i = 0; i < 4; ++i)
                #pragma unroll
                for (int j = 0; j < 4; ++j)
                    acc[i][j] += a[i].x * b[j].x + a[i].y * b[j].y
                               + a[i].z * b[j].z + a[i].w * b[j].w;
        }
        __syncthreads();
    }
    #pragma unroll
    for (int i = 0; i < 4; ++i) {
        int m = m0 + ty * 4 + i;
        int n = n0 + tx * 4;
        ushort4 o;
        o.x = f2bf(acc[i][0] + bih[n + 0] + bhh[n + 0]);
        o.y = f2bf(acc[i][1] + bih[n + 1] + bhh[n + 1]);
        o.z = f2bf(acc[i][2] + bih[n + 2] + bhh[n + 2]);
        o.w = f2bf(acc[i][3] + bih[n + 3] + bhh[n + 3]);
        *(ushort4*)&G[(size_t)m * 1024 + n] = o;
    }
}

// ---------- persistent LSTM layer ----------
// grid: 32 blocks (batch chunks of 16), 512 threads = 8 waves.
// Wave w owns h-cols [w*32, w*32+32) x 4 gate types = 128 Whh rows.
// Weights as MFMA B-frags: 64 frags/wave (cg{2} x type{4} x ks{8}); first
// RFRAGS in VGPRs, rest in LDS. h lives in LDS [16][264] bf16 (pad 8).
#define RFRAGS 46
#define LFRAGS 18
#define LDS_HBYTES 8448            // 16*264*2
#define LDS_TOTAL (LDS_HBYTES + LFRAGS * 8 * 1024)   // 155904

__global__ __launch_bounds__(512, 2) void lstm_persist(
    const unsigned short* __restrict__ G,    // [128][512][1024] bf16 (bias included)
    const float* __restrict__ Whh,           // [1024][256] f32
    unsigned short* __restrict__ h0out,      // layer0: [512][128][256] bf16, else nullptr
    float* __restrict__ hlast)               // [512][256] f32, written at t==127
{
    extern __shared__ char smem[];
    char* ldsW = smem + LDS_HBYTES;

    const int lid = threadIdx.x;
    const int w = lid >> 6;
    const int l = lid & 63;
    const int l15 = l & 15, lg = l >> 4;
    const int bc = blockIdx.x;

    // ---- load weights: frag f -> (cg=f>>5, type=(f>>3)&3, ks=f&7) ----
    bf16x8 wreg[RFRAGS];
    #pragma unroll
    for (int f = 0; f < RFRAGS; ++f) {
        const int cg = f >> 5, type = (f >> 3) & 3, ks = f & 7;
        const int grow = type * 256 + w * 32 + cg * 16 + l15;
        const int k0 = ks * 32 + lg * 8;
        const float* src = Whh + (size_t)grow * 256 + k0;
        float4 lo = *(const float4*)src;
        float4 hi = *(const float4*)(src + 4);
        bf16x8 v;
        v[0] = (short)f2bf(lo.x); v[1] = (short)f2bf(lo.y);
        v[2] = (short)f2bf(lo.z); v[3] = (short)f2bf(lo.w);
        v[4] = (short)f2bf(hi.x); v[5] = (short)f2bf(hi.y);
        v[6] = (short)f2bf(hi.z); v[7] = (short)f2bf(hi.w);
        wreg[f] = v;
    }
    for (int f = RFRAGS; f < 64; ++f) {
        const int cg = f >> 5, type = (f >> 3) & 3, ks = f & 7;
        const int grow = type * 256 + w * 32 + cg * 16 + l15;
        const int k0 = ks * 32 + lg * 8;
        const float* src = Whh + (size_t)grow * 256 + k0;
        float4 lo = *(const float4*)src;
        float4 hi = *(const float4*)(src + 4);
        bf16x8 v;
        v[0] = (short)f2bf(lo.x); v[1] = (short)f2bf(lo.y);
        v[2] = (short)f2bf(lo.z); v[3] = (short)f2bf(lo.w);
        v[4] = (short)f2bf(hi.x); v[5] = (short)f2bf(hi.y);
        v[6] = (short)f2bf(hi.z); v[7] = (short)f2bf(hi.w);
        *(bf16x8*)(ldsW + (size_t)(w * LFRAGS + (f - RFRAGS)) * 1024 + l * 16) = v;
    }

    // zero h buffer
    for (int i = lid; i < 16 * 264; i += 512) ((unsigned short*)smem)[i] = 0;
    __syncthreads();

    float cst[2][4] = {};
    unsigned short hb16[2][4];

    for (int t = 0; t < 128; ++t) {
        const unsigned short* Gt = G + ((size_t)t * 512 + bc * 16) * 1024;

        #pragma unroll
        for (int cg = 0; cg < 2; ++cg) {
            // issue G loads early (consumed after the MFMA block)
            unsigned short gv[4][4];
            #pragma unroll
            for (int type = 0; type < 4; ++type)
                #pragma unroll
                for (int r = 0; r < 4; ++r)
                    gv[type][r] = Gt[(size_t)(lg * 4 + r) * 1024
                                     + type * 256 + w * 32 + cg * 16 + l15];

            f32x4 acc[4];
            #pragma unroll
            for (int type = 0; type < 4; ++type) acc[type] = (f32x4){0.f, 0.f, 0.f, 0.f};

            #pragma unroll
            for (int ks = 0; ks < 8; ++ks) {
                bf16x8 a = *(const bf16x8*)(smem + l15 * 528 + ks * 64 + lg * 16);
                #pragma unroll
                for (int type = 0; type < 4; ++type) {
                    const int f = cg * 32 + type * 8 + ks;
                    bf16x8 b;
                    if (f < RFRAGS) b = wreg[f];
                    else b = *(const bf16x8*)(ldsW + (w * LFRAGS + (f - RFRAGS)) * 1024 + l * 16);
                    acc[type] = __builtin_amdgcn_mfma_f32_16x16x32_bf16(a, b, acc[type], 0, 0, 0);
                }
            }

            #pragma unroll
            for (int r = 0; r < 4; ++r) {
                float p0 = acc[0][r] + bf2f(gv[0][r]);
                float p1 = acc[1][r] + bf2f(gv[1][r]);
                float p2 = acc[2][r] + bf2f(gv[2][r]);
                float p3 = acc[3][r] + bf2f(gv[3][r]);
                float ii = sigm(p0), ff = sigm(p1), gg = ftanh(p2), oo = sigm(p3);
                float cn = ff * cst[cg][r] + ii * gg;
                cst[cg][r] = cn;
                float hn = oo * ftanh(cn);
                hb16[cg][r] = f2bf(hn);
                if (h0out)
                    h0out[((size_t)(bc * 16 + lg * 4 + r) * 128 + t) * 256
                          + w * 32 + cg * 16 + l15] = hb16[cg][r];
                if (t == 127)
                    hlast[(size_t)(bc * 16 + lg * 4 + r) * 256
                          + w * 32 + cg * 16 + l15] = hn;
            }
        }

        __syncthreads();   // all waves done reading h(t-1)
        #pragma unroll
        for (int cg = 0; cg < 2; ++cg)
            #pragma unroll
            for (int r = 0; r < 4; ++r)
                *(unsigned short*)(smem + (lg * 4 + r) * 528
                                   + (w * 32 + cg * 16 + l15) * 2) = hb16[cg][r];
        __syncthreads();   // h(t) visible
    }
}

// ---------- FC GEMM: logits[m][n] = h[m,:]·fcW[n,:] + fcb[n] ----------
__global__ __launch_bounds__(256) void gemm_fc(
    const float* __restrict__ h, const float* __restrict__ fcW,
    const float* __restrict__ fcb, float* __restrict__ logits)
{
    __shared__ float As[32][260];
    __shared__ float Bs[32][260];
    const int lid = threadIdx.x;
    const int tx = lid & 15, ty = lid >> 4;
    const int n0 = blockIdx.x * 64, m0 = blockIdx.y * 64;
    float acc[4][4] = {};

    for (int kk = 0; kk < 256; kk += 128) {
        #pragma unroll
        for (int it = 0; it < 8; ++it) {
            int idx = lid + it * 256;
            int r = idx >> 5, q = idx & 31;
            int m = m0 + r;
            *(float4*)&As[q][r * 4] = *(const float4*)&h[(size_t)m * 256 + kk + q * 4];
        }
        #pragma unroll
        for (int it = 0; it < 8; ++it) {
            int idx = lid + it * 256;
            int r = idx >> 5, q = idx & 31;
            int g = n0 + r;
            float4 v = make_float4(0.f, 0.f, 0.f, 0.f);
            if (g < 50257) v = *(const float4*)&fcW[(size_t)g * 256 + kk + q * 4];
            *(float4*)&Bs[q][r * 4] = v;
        }
        __syncthreads();
        #pragma unroll 4
        for (int q = 0; q < 32; ++q) {
            float4 a[4], b[4];
            #pragma unroll
            for (int i = 0; i < 4; ++i) a[i] = *(const float4*)&As[q][(ty * 4 + i) * 4];
            #pragma unroll
            for (int j = 0; j < 4; ++j) b[j] = *(const float4*)&Bs[q][(tx * 4 + j) * 4];
            #pragma unroll
            for (int i = 0; i < 4; ++i)
                #pragma unroll
                for (int j = 0; j < 4; ++j)
                    acc[i][j] += a[i].x * b[j].x + a[i].y * b[j].y
                               + a[i].z * b[j].z + a[i].w * b[j].w;
        }
        __syncthreads();
    }
    #pragma unroll
    for (int i = 0; i < 4; ++i) {
        int m = m0 + ty * 4 + i;
        #pragma unroll
        for (int jj = 0; jj < 4; ++jj) {
            int n = n0 + tx * 4 + jj;
            if (n < 50257)
                logits[(size_t)m * 50257 + n] = acc[i][jj] + fcb[n];
        }
    }
}

// ---------- row softmax over 50257 ----------
__global__ __launch_bounds__(256) void softmax_rows(
    const float* __restrict__ logits, float* __restrict__ out)
{
    const int b = blockIdx.x;
    const int lid = threadIdx.x;
    const float* row = logits + (size_t)b * 50257;
    __shared__ float red[256];

    float m = -3.4e38f;
    for (int v = lid; v < 50257; v += 256) m = fmaxf(m, row[v]);
    red[lid] = m; __syncthreads();
    for (int s = 128; s > 0; s >>= 1) {
        if (lid < s) red[lid] = fmaxf(red[lid], red[lid + s]);
        __syncthreads();
    }
    m = red[0]; __syncthreads();

    float sum = 0.f;
    for (int v = lid; v < 50257; v += 256) sum += __expf(row[v] - m);
    red[lid] = sum; __syncthreads();
    for (int s = 128; s > 0; s >>= 1) {
        if (lid < s) red[lid] += red[lid + s];
        __syncthreads();
    }
    float inv = 1.0f / red[0];

    float* orow = out + (size_t)b * 50257;
    for (int v = lid; v < 50257; v += 256) orow[v] = __expf(row[v] - m) * inv;
}

// ---------- host ----------
extern "C" void kernel_launch(void* const* d_in, const int* in_sizes, int n_in,
                              void* d_out, int out_size, void* d_ws, size_t ws_size,
                              hipStream_t stream) {
    (void)in_sizes; (void)n_in; (void)out_size; (void)ws_size;
    const float* x    = (const float*)d_in[0];
    const float* Wih0 = (const float*)d_in[1];
    const float* Whh0 = (const float*)d_in[2];
    const float* bih0 = (const float*)d_in[3];
    const float* bhh0 = (const float*)d_in[4];
    const float* Wih1 = (const float*)d_in[5];
    const float* Whh1 = (const float*)d_in[6];
    const float* bih1 = (const float*)d_in[7];
    const float* bhh1 = (const float*)d_in[8];
    const float* fcW  = (const float*)d_in[9];
    const float* fcb  = (const float*)d_in[10];
    float* out = (float*)d_out;

    char* ws = (char*)d_ws;
    unsigned short* G     = (unsigned short*)ws;                    // 134,217,728 B
    unsigned short* h0all = (unsigned short*)(ws + 134217728);      // 33,554,432 B
    float* hA = (float*)(ws + 167772160);                           // 512*256 f32 (scratch)
    float* hB = (float*)(ws + 168296448);                           // 512*256 f32
    float* logits = (float*)ws;                                     // reuse G region

    static bool attr_set = false;
    if (!attr_set) {
        hipFuncSetAttribute((const void*)lstm_persist,
                            hipFuncAttributeMaxDynamicSharedMemorySize, LDS_TOTAL);
        attr_set = true;
    }

    // ----- layer 0 -----
    gemm_gates<128, false><<<dim3(16, 1024), 256, 0, stream>>>(x, Wih0, bih0, bhh0, G);
    lstm_persist<<<32, 512, LDS_TOTAL, stream>>>(G, Whh0, h0all, hA);
    // ----- layer 1 -----
    gemm_gates<256, true><<<dim3(16, 1024), 256, 0, stream>>>(h0all, Wih1, bih1, bhh1, G);
    lstm_persist<<<32, 512, LDS_TOTAL, stream>>>(G, Whh1, nullptr, hB);
    // ----- FC + softmax -----
    gemm_fc<<<dim3(786, 8), 256, 0, stream>>>(hB, fcW, fcb, logits);
    softmax_rows<<<512, 256, 0, stream>>>(logits, out);
}

// Round 3
// 1999.028 us; speedup vs baseline: 2.6482x; 1.7901x over previous
//
#include <hip/hip_runtime.h>
#include <hip/hip_bf16.h>

// ---------- helpers ----------
__device__ __forceinline__ float bf2f(unsigned short u) {
    union { unsigned int i; float f; } x; x.i = ((unsigned int)u) << 16; return x.f;
}
__device__ __forceinline__ unsigned short f2bf(float f) {
    union { float f; unsigned int i; } x; x.f = f;
    unsigned int r = x.i + 0x7fffu + ((x.i >> 16) & 1u);   // RTNE
    return (unsigned short)(r >> 16);
}
__device__ __forceinline__ float sigm(float x) { return 1.0f / (1.0f + __expf(-x)); }
__device__ __forceinline__ float ftanh(float x) {
    x = fminf(15.f, fmaxf(-15.f, x));
    float t = __expf(2.0f * x);
    return (t - 1.0f) / (t + 1.0f);
}

typedef __attribute__((ext_vector_type(8))) short bf16x8;
typedef __attribute__((ext_vector_type(4))) float f32x4;

__device__ __forceinline__ bf16x8 pack8(float4 a, float4 b) {
    bf16x8 v;
    v[0] = (short)f2bf(a.x); v[1] = (short)f2bf(a.y);
    v[2] = (short)f2bf(a.z); v[3] = (short)f2bf(a.w);
    v[4] = (short)f2bf(b.x); v[5] = (short)f2bf(b.y);
    v[6] = (short)f2bf(b.z); v[7] = (short)f2bf(b.w);
    return v;
}

// ---------- fp32 -> bf16 convert (8 elems/thread) ----------
__global__ __launch_bounds__(256) void cvt_f32_bf16(
    const float* __restrict__ in, unsigned short* __restrict__ out, int n8)
{
    int i = blockIdx.x * 256 + threadIdx.x;
    if (i >= n8) return;
    float4 a = *(const float4*)(in + (size_t)i * 8);
    float4 b = *(const float4*)(in + (size_t)i * 8 + 4);
    *(bf16x8*)(out + (size_t)i * 8) = pack8(a, b);
}

// ---------- x [b][t][128] fp32 -> xb [t*512+b][128] bf16 ----------
__global__ __launch_bounds__(256) void cvt_x_transpose(
    const float* __restrict__ in, unsigned short* __restrict__ out)
{
    int c = blockIdx.x * 256 + threadIdx.x;      // 1,048,576 chunks of 8
    int b = c >> 11, t = (c >> 4) & 127, kc = c & 15;
    const float* src = in + (((size_t)b * 128 + t) * 16 + kc) * 8;
    float4 a = *(const float4*)src;
    float4 bb = *(const float4*)(src + 4);
    *(bf16x8*)(out + (((size_t)t * 512 + b) * 16 + kc) * 8) = pack8(a, bb);
}

// ---------- MFMA GEMM: C[m][n] = A[m,:]·B[n,:] + bias, bf16 inputs ----------
// 128x128 tile, BK=64, 256 threads = 4 waves (2x2), 64x64 out per wave.
template<int K, bool OUT_BF16, bool GUARD_N>
__global__ __launch_bounds__(256) void gemm_mfma(
    const unsigned short* __restrict__ A,    // [M][K] bf16
    const unsigned short* __restrict__ Bm,   // [N][K] bf16
    const float* __restrict__ bias0,
    const float* __restrict__ bias1,         // may be null
    void* __restrict__ Cptr, long ldC, int N)
{
    constexpr int LDA = 72;                   // 64 + 8 pad (row = 144 B = 9*16)
    __shared__ unsigned short As[128 * LDA];
    __shared__ unsigned short Bs[128 * LDA];
    const int tid = threadIdx.x;
    const int lane = tid & 63;
    const int l15 = lane & 15, lg = lane >> 4;
    const int wid = tid >> 6;
    const int wr = wid >> 1, wc = wid & 1;
    const int m0 = blockIdx.y * 128, n0 = blockIdx.x * 128;
    const int srow = tid >> 3;                // 0..31
    const int scol = (tid & 7) * 8;           // 0..56

    f32x4 acc[4][4];
    #pragma unroll
    for (int mi = 0; mi < 4; ++mi)
        #pragma unroll
        for (int ni = 0; ni < 4; ++ni)
            acc[mi][ni] = (f32x4){0.f, 0.f, 0.f, 0.f};

    for (int kt = 0; kt < K / 64; ++kt) {
        bf16x8 avals[4], bvals[4];
        #pragma unroll
        for (int i = 0; i < 4; ++i) {
            avals[i] = *(const bf16x8*)(A + (size_t)(m0 + i * 32 + srow) * K + kt * 64 + scol);
            int brow = n0 + i * 32 + srow;
            if (GUARD_N) brow = (brow < N) ? brow : (N - 1);
            bvals[i] = *(const bf16x8*)(Bm + (size_t)brow * K + kt * 64 + scol);
        }
        __syncthreads();   // previous iter's reads complete
        #pragma unroll
        for (int i = 0; i < 4; ++i) {
            *(bf16x8*)&As[(i * 32 + srow) * LDA + scol] = avals[i];
            *(bf16x8*)&Bs[(i * 32 + srow) * LDA + scol] = bvals[i];
        }
        __syncthreads();
        #pragma unroll
        for (int ks = 0; ks < 2; ++ks) {
            bf16x8 af[4], bf[4];
            #pragma unroll
            for (int mi = 0; mi < 4; ++mi)
                af[mi] = *(const bf16x8*)&As[(wr * 64 + mi * 16 + l15) * LDA + ks * 32 + lg * 8];
            #pragma unroll
            for (int ni = 0; ni < 4; ++ni)
                bf[ni] = *(const bf16x8*)&Bs[(wc * 64 + ni * 16 + l15) * LDA + ks * 32 + lg * 8];
            #pragma unroll
            for (int mi = 0; mi < 4; ++mi)
                #pragma unroll
                for (int ni = 0; ni < 4; ++ni)
                    acc[mi][ni] = __builtin_amdgcn_mfma_f32_16x16x32_bf16(
                        af[mi], bf[ni], acc[mi][ni], 0, 0, 0);
        }
    }

    #pragma unroll
    for (int ni = 0; ni < 4; ++ni) {
        int n = n0 + wc * 64 + ni * 16 + l15;
        bool nok = (!GUARD_N) || (n < N);
        float bsum = 0.f;
        if (nok) { bsum = bias0[n]; if (bias1) bsum += bias1[n]; }
        #pragma unroll
        for (int mi = 0; mi < 4; ++mi) {
            int m = m0 + wr * 64 + mi * 16 + lg * 4;
            #pragma unroll
            for (int r = 0; r < 4; ++r) {
                float v = acc[mi][ni][r] + bsum;
                if (nok) {
                    if (OUT_BF16)
                        ((unsigned short*)Cptr)[(size_t)(m + r) * ldC + n] = f2bf(v);
                    else
                        ((float*)Cptr)[(size_t)(m + r) * ldC + n] = v;
                }
            }
        }
    }
}

// ---------- persistent LSTM layer ----------
#define RFRAGS 46
#define LFRAGS 18
#define LDS_HBYTES 8448            // 16*264*2
#define LDS_TOTAL (LDS_HBYTES + LFRAGS * 8 * 1024)   // 155904

__global__ __launch_bounds__(512, 2) void lstm_persist(
    const unsigned short* __restrict__ G,    // [128][512][1024] bf16 (bias included)
    const float* __restrict__ Whh,           // [1024][256] f32
    unsigned short* __restrict__ h0out,      // layer0: [t*512+b][256] bf16, else nullptr
    unsigned short* __restrict__ hlast)      // layer1: [512][256] bf16 at t=127, else nullptr
{
    extern __shared__ char smem[];
    char* ldsW = smem + LDS_HBYTES;

    const int lid = threadIdx.x;
    const int w = lid >> 6;
    const int l = lid & 63;
    const int l15 = l & 15, lg = l >> 4;
    const int bc = blockIdx.x;

    bf16x8 wreg[RFRAGS];
    #pragma unroll
    for (int f = 0; f < RFRAGS; ++f) {
        const int cg = f >> 5, type = (f >> 3) & 3, ks = f & 7;
        const int grow = type * 256 + w * 32 + cg * 16 + l15;
        const int k0 = ks * 32 + lg * 8;
        const float* src = Whh + (size_t)grow * 256 + k0;
        wreg[f] = pack8(*(const float4*)src, *(const float4*)(src + 4));
    }
    for (int f = RFRAGS; f < 64; ++f) {
        const int cg = f >> 5, type = (f >> 3) & 3, ks = f & 7;
        const int grow = type * 256 + w * 32 + cg * 16 + l15;
        const int k0 = ks * 32 + lg * 8;
        const float* src = Whh + (size_t)grow * 256 + k0;
        *(bf16x8*)(ldsW + (size_t)(w * LFRAGS + (f - RFRAGS)) * 1024 + l * 16) =
            pack8(*(const float4*)src, *(const float4*)(src + 4));
    }

    for (int i = lid; i < 16 * 264; i += 512) ((unsigned short*)smem)[i] = 0;
    __syncthreads();

    float cst[2][4] = {};
    unsigned short hb16[2][4];

    for (int t = 0; t < 128; ++t) {
        const unsigned short* Gt = G + ((size_t)t * 512 + bc * 16) * 1024;

        #pragma unroll
        for (int cg = 0; cg < 2; ++cg) {
            unsigned short gv[4][4];
            #pragma unroll
            for (int type = 0; type < 4; ++type)
                #pragma unroll
                for (int r = 0; r < 4; ++r)
                    gv[type][r] = Gt[(size_t)(lg * 4 + r) * 1024
                                     + type * 256 + w * 32 + cg * 16 + l15];

            f32x4 acc[4];
            #pragma unroll
            for (int type = 0; type < 4; ++type) acc[type] = (f32x4){0.f, 0.f, 0.f, 0.f};

            #pragma unroll
            for (int ks = 0; ks < 8; ++ks) {
                bf16x8 a = *(const bf16x8*)(smem + l15 * 528 + ks * 64 + lg * 16);
                #pragma unroll
                for (int type = 0; type < 4; ++type) {
                    const int f = cg * 32 + type * 8 + ks;
                    bf16x8 b;
                    if (f < RFRAGS) b = wreg[f];
                    else b = *(const bf16x8*)(ldsW + (w * LFRAGS + (f - RFRAGS)) * 1024 + l * 16);
                    acc[type] = __builtin_amdgcn_mfma_f32_16x16x32_bf16(a, b, acc[type], 0, 0, 0);
                }
            }

            #pragma unroll
            for (int r = 0; r < 4; ++r) {
                float p0 = acc[0][r] + bf2f(gv[0][r]);
                float p1 = acc[1][r] + bf2f(gv[1][r]);
                float p2 = acc[2][r] + bf2f(gv[2][r]);
                float p3 = acc[3][r] + bf2f(gv[3][r]);
                float ii = sigm(p0), ff = sigm(p1), gg = ftanh(p2), oo = sigm(p3);
                float cn = ff * cst[cg][r] + ii * gg;
                cst[cg][r] = cn;
                float hn = oo * ftanh(cn);
                hb16[cg][r] = f2bf(hn);
                if (h0out)
                    h0out[((size_t)t * 512 + bc * 16 + lg * 4 + r) * 256
                          + w * 32 + cg * 16 + l15] = hb16[cg][r];
                if (hlast && t == 127)
                    hlast[(size_t)(bc * 16 + lg * 4 + r) * 256
                          + w * 32 + cg * 16 + l15] = hb16[cg][r];
            }
        }

        __syncthreads();
        #pragma unroll
        for (int cg = 0; cg < 2; ++cg)
            #pragma unroll
            for (int r = 0; r < 4; ++r)
                *(unsigned short*)(smem + (lg * 4 + r) * 528
                                   + (w * 32 + cg * 16 + l15) * 2) = hb16[cg][r];
        __syncthreads();
    }
}

// ---------- row softmax over 50257 ----------
__global__ __launch_bounds__(256) void softmax_rows(
    const float* __restrict__ logits, float* __restrict__ out)
{
    const int b = blockIdx.x;
    const int lid = threadIdx.x;
    const float* row = logits + (size_t)b * 50257;
    __shared__ float red[256];

    float m = -3.4e38f;
    for (int v = lid; v < 50257; v += 256) m = fmaxf(m, row[v]);
    red[lid] = m; __syncthreads();
    for (int s = 128; s > 0; s >>= 1) {
        if (lid < s) red[lid] = fmaxf(red[lid], red[lid + s]);
        __syncthreads();
    }
    m = red[0]; __syncthreads();

    float sum = 0.f;
    for (int v = lid; v < 50257; v += 256) sum += __expf(row[v] - m);
    red[lid] = sum; __syncthreads();
    for (int s = 128; s > 0; s >>= 1) {
        if (lid < s) red[lid] += red[lid + s];
        __syncthreads();
    }
    float inv = 1.0f / red[0];

    float* orow = out + (size_t)b * 50257;
    for (int v = lid; v < 50257; v += 256) orow[v] = __expf(row[v] - m) * inv;
}

// ---------- host ----------
extern "C" void kernel_launch(void* const* d_in, const int* in_sizes, int n_in,
                              void* d_out, int out_size, void* d_ws, size_t ws_size,
                              hipStream_t stream) {
    (void)in_sizes; (void)n_in; (void)out_size; (void)ws_size;
    const float* x    = (const float*)d_in[0];
    const float* Wih0 = (const float*)d_in[1];
    const float* Whh0 = (const float*)d_in[2];
    const float* bih0 = (const float*)d_in[3];
    const float* bhh0 = (const float*)d_in[4];
    const float* Wih1 = (const float*)d_in[5];
    const float* Whh1 = (const float*)d_in[6];
    const float* bih1 = (const float*)d_in[7];
    const float* bhh1 = (const float*)d_in[8];
    const float* fcW  = (const float*)d_in[9];
    const float* fcb  = (const float*)d_in[10];
    float* out = (float*)d_out;

    char* ws = (char*)d_ws;
    unsigned short* G      = (unsigned short*)ws;                 // 134,217,728 B
    unsigned short* h0all  = (unsigned short*)(ws + 134217728);   // 33,554,432 B
    unsigned short* xb     = h0all;                               // alias: dead before lstm0 writes h0all
    char* misc             = ws + 167772160;
    unsigned short* W0b    = (unsigned short*)(misc);             // 262,144 B
    unsigned short* W1b    = (unsigned short*)(misc + 262144);    // 524,288 B
    unsigned short* hlastb = (unsigned short*)(misc + 786432);    // 262,144 B
    float* logits          = (float*)ws;                          // 102,926,336 B (reuses G)
    unsigned short* fcWb   = (unsigned short*)(ws + 103809024);   // 25,731,584 B (in G region, past logits)

    static bool attr_set = false;
    if (!attr_set) {
        hipFuncSetAttribute((const void*)lstm_persist,
                            hipFuncAttributeMaxDynamicSharedMemorySize, LDS_TOTAL);
        attr_set = true;
    }

    // ----- layer 0 -----
    cvt_x_transpose<<<4096, 256, 0, stream>>>(x, xb);
    cvt_f32_bf16<<<64, 256, 0, stream>>>(Wih0, W0b, 16384);
    gemm_mfma<128, true, false><<<dim3(8, 512), 256, 0, stream>>>(
        xb, W0b, bih0, bhh0, G, 1024, 1024);
    lstm_persist<<<32, 512, LDS_TOTAL, stream>>>(G, Whh0, h0all, nullptr);
    // ----- layer 1 -----
    cvt_f32_bf16<<<128, 256, 0, stream>>>(Wih1, W1b, 32768);
    gemm_mfma<256, true, false><<<dim3(8, 512), 256, 0, stream>>>(
        h0all, W1b, bih1, bhh1, G, 1024, 1024);
    lstm_persist<<<32, 512, LDS_TOTAL, stream>>>(G, Whh1, nullptr, hlastb);
    // ----- FC + softmax -----
    cvt_f32_bf16<<<6283, 256, 0, stream>>>(fcW, fcWb, 1608224);
    gemm_mfma<256, false, true><<<dim3(393, 4), 256, 0, stream>>>(
        hlastb, fcWb, fcb, nullptr, logits, 50257, 50257);
    softmax_rows<<<512, 256, 0, stream>>>(logits, out);
}